// Round 6
// baseline (164.427 us; speedup 1.0000x reference)
//
#include <hip/hip_runtime.h>
#include <math.h>

// Sparse 3D max-pool (kernel=stride=2), gather v5: one wave per segment,
// all bucket rows issued back-to-back (max MLP, single wait region).
// zero -> bucket scatter -> gather -> overflow CAS cleanup (statistically empty).

#define CHANNELS 64
#define COARSE_RES 64
#define NSEG (COARSE_RES * COARSE_RES * COARSE_RES)  // 262144
#define CAP 16
#define MAXOVF 65536

__global__ void zero_kernel(int* __restrict__ buf, int n) {
    int i = blockIdx.x * blockDim.x + threadIdx.x;
    int stride = gridDim.x * blockDim.x;
    for (; i < n; i += stride) buf[i] = 0;
}

__global__ void scatter_kernel(const int* __restrict__ coords,
                               int* __restrict__ cursor,
                               int* __restrict__ ovf,       // [0]=count, data at +16
                               int* __restrict__ indices,
                               int n) {
    int p = blockIdx.x * blockDim.x + threadIdx.x;
    if (p >= n) return;
    int ci = coords[3 * p + 0] >> 1;
    int cj = coords[3 * p + 1] >> 1;
    int ck = coords[3 * p + 2] >> 1;
    int seg = (ci * COARSE_RES + cj) * COARSE_RES + ck;
    int pos = atomicAdd(&cursor[seg], 1);
    if (pos < CAP) {
        indices[seg * CAP + pos] = p;
    } else {
        int o = atomicAdd(&ovf[0], 1);
        if (o < MAXOVF) {
            ovf[16 + 2 * o + 0] = p;
            ovf[16 + 2 * o + 1] = seg;
        }
    }
}

// One wave per segment, lane = channel. All rows issued before any use:
// up to 16 independent 256B row loads in flight per wave. Ragged tail is
// clamp-duplicated (same wave-uniform address -> cache-merged, max-safe).
__global__ __launch_bounds__(256) void gather_max_kernel(
        const float* __restrict__ feat,
        const int* __restrict__ indices,
        const int* __restrict__ cursor,
        float* __restrict__ out) {
    int wave = (blockIdx.x * blockDim.x + threadIdx.x) >> 6;
    int lane = threadIdx.x & 63;

    int cnt = cursor[wave];                         // wave-uniform
    int idx = indices[(long)wave * CAP + (lane & 15)];  // 64B line, coalesced
    cnt = min(cnt, CAP);

    if (cnt == 0) {
        out[(long)wave * CHANNELS + lane] = 0.0f;
        return;
    }

    int cm1 = cnt - 1;
#define ROW(r) feat[(long)__shfl(idx, min((r), cm1)) * CHANNELS + lane]
    float f0, f1, f2, f3, f4, f5, f6, f7, f8, f9, f10, f11, f12, f13, f14, f15;
    f0 = ROW(0); f1 = ROW(1); f2 = ROW(2); f3 = ROW(3);
    if (cnt > 4)  { f4  = ROW(4);  f5  = ROW(5);  f6  = ROW(6);  f7  = ROW(7);  }
    if (cnt > 8)  { f8  = ROW(8);  f9  = ROW(9);  f10 = ROW(10); f11 = ROW(11); }
    if (cnt > 12) { f12 = ROW(12); f13 = ROW(13); f14 = ROW(14); f15 = ROW(15); }
#undef ROW

    float m = fmaxf(fmaxf(f0, f1), fmaxf(f2, f3));
    if (cnt > 4)  m = fmaxf(m, fmaxf(fmaxf(f4, f5),   fmaxf(f6, f7)));
    if (cnt > 8)  m = fmaxf(m, fmaxf(fmaxf(f8, f9),   fmaxf(f10, f11)));
    if (cnt > 12) m = fmaxf(m, fmaxf(fmaxf(f12, f13), fmaxf(f14, f15)));

    out[(long)wave * CHANNELS + lane] = m;
}

// Exact cleanup for bucket-overflow points (empty for this input). CAS float max.
__global__ void overflow_kernel(const float* __restrict__ feat,
                                const int* __restrict__ ovf,
                                float* __restrict__ out) {
    int n = min(ovf[0], MAXOVF);
    int total = n * CHANNELS;
    int stride = gridDim.x * blockDim.x;
    for (int k = blockIdx.x * blockDim.x + threadIdx.x; k < total; k += stride) {
        int e = k >> 6;
        int c = k & 63;
        int p = ovf[16 + 2 * e + 0];
        int seg = ovf[16 + 2 * e + 1];
        float v = feat[(long)p * CHANNELS + c];
        int* addr = (int*)&out[(long)seg * CHANNELS + c];
        int old = *addr;
        while (__int_as_float(old) < v) {
            int assumed = old;
            old = atomicCAS(addr, assumed, __float_as_int(v));
            if (old == assumed) break;
        }
    }
}

extern "C" void kernel_launch(void* const* d_in, const int* in_sizes, int n_in,
                              void* d_out, int out_size, void* d_ws, size_t ws_size,
                              hipStream_t stream) {
    const float* feat = (const float*)d_in[0];
    const int* coords = (const int*)d_in[1];
    int npoints = in_sizes[0] / CHANNELS;  // 1,000,000

    // ws layout (ints): cursor[NSEG] | ovf[16 + 2*MAXOVF] | indices[NSEG*CAP]
    int* cursor  = (int*)d_ws;
    int* ovf     = cursor + NSEG;
    int* indices = ovf + 16 + 2 * MAXOVF;

    const int BLOCK = 256;

    zero_kernel<<<512, BLOCK, 0, stream>>>(cursor, NSEG + 16);

    int grid_pts = (npoints + BLOCK - 1) / BLOCK;
    scatter_kernel<<<grid_pts, BLOCK, 0, stream>>>(coords, cursor, ovf, indices, npoints);

    int grid_gather = NSEG / (BLOCK / 64);  // 65536 blocks, 4 waves each
    gather_max_kernel<<<grid_gather, BLOCK, 0, stream>>>(feat, indices, cursor, (float*)d_out);

    overflow_kernel<<<16, BLOCK, 0, stream>>>(feat, ovf, (float*)d_out);
}

// Round 7
// 145.571 us; speedup vs baseline: 1.1295x; 1.1295x over previous
//
#include <hip/hip_runtime.h>
#include <math.h>

// Sparse 3D max-pool (kernel=stride=2), gather v6: strip-per-wave with
// explicit 4-slot software pipeline (16 row-loads in flight per wave).
// zero -> bucket scatter -> strip gather -> overflow CAS cleanup (empty).

#define CHANNELS 64
#define COARSE_RES 64
#define NSEG (COARSE_RES * COARSE_RES * COARSE_RES)  // 262144
#define CAP 16
#define MAXOVF 65536
#define SPW 8  // segments per wave

__global__ void zero_kernel(int* __restrict__ buf, int n) {
    int i = blockIdx.x * blockDim.x + threadIdx.x;
    int stride = gridDim.x * blockDim.x;
    for (; i < n; i += stride) buf[i] = 0;
}

__global__ void scatter_kernel(const int* __restrict__ coords,
                               int* __restrict__ cursor,
                               int* __restrict__ ovf,       // [0]=count, data at +16
                               int* __restrict__ indices,
                               int n) {
    int p = blockIdx.x * blockDim.x + threadIdx.x;
    if (p >= n) return;
    int ci = coords[3 * p + 0] >> 1;
    int cj = coords[3 * p + 1] >> 1;
    int ck = coords[3 * p + 2] >> 1;
    int seg = (ci * COARSE_RES + cj) * COARSE_RES + ck;
    int pos = atomicAdd(&cursor[seg], 1);
    if (pos < CAP) {
        indices[seg * CAP + pos] = p;
    } else {
        int o = atomicAdd(&ovf[0], 1);
        if (o < MAXOVF) {
            ovf[16 + 2 * o + 0] = p;
            ovf[16 + 2 * o + 1] = seg;
        }
    }
}

// One wave per 8 consecutive segments. Counts + all 128 bucket indices
// preloaded into registers (shfl-extracted). The point list is consumed in
// chunks of 4 rows via a 4-slot rotating software pipeline: 16 independent
// 256B row loads in flight per wave. Tail rows clamp-duplicated (max-safe).
__global__ __launch_bounds__(256) void gather_strip_kernel(
        const float* __restrict__ feat,
        const int* __restrict__ indices,
        const int* __restrict__ cursor,
        float* __restrict__ out) {
    int wave = (blockIdx.x * blockDim.x + threadIdx.x) >> 6;
    int lane = threadIdx.x & 63;
    long segbase = (long)wave * SPW;

    int cnt_l = 0;
    if (lane < SPW) {
        cnt_l = cursor[segbase + lane];
        if (cnt_l > CAP) cnt_l = CAP;
    }
    // 128 indices of the strip: 2 ints per lane, fully coalesced 512B
    int2 idx2 = reinterpret_cast<const int2*>(indices + segbase * CAP)[lane];

    int s = 0, t = 0, cs = 0;
    float m = -INFINITY;

    #define SKIP_EMPTIES()                                         \
        for (;;) {                                                 \
            if (s >= SPW) break;                                   \
            cs = __shfl(cnt_l, s);                                 \
            if (cs > 0) break;                                     \
            out[(segbase + s) * CHANNELS + lane] = 0.0f;           \
            ++s;                                                   \
        }

    #define EXTRACT(r, dst) {                                      \
        int lsrc = (s << 3) + ((r) >> 1);                          \
        int lo_ = __shfl(idx2.x, lsrc);                            \
        int hi_ = __shfl(idx2.y, lsrc);                            \
        dst = ((r) & 1) ? hi_ : lo_; }

    #define ISSUE(F0, F1, F2, F3, FLUSH, SEG) {                    \
        int r1_ = min(t + 1, cs - 1);                              \
        int r2_ = min(t + 2, cs - 1);                              \
        int r3_ = min(t + 3, cs - 1);                              \
        int p0_, p1_, p2_, p3_;                                    \
        EXTRACT(t,   p0_); EXTRACT(r1_, p1_);                      \
        EXTRACT(r2_, p2_); EXTRACT(r3_, p3_);                      \
        F0 = feat[(long)p0_ * CHANNELS + lane];                    \
        F1 = feat[(long)p1_ * CHANNELS + lane];                    \
        F2 = feat[(long)p2_ * CHANNELS + lane];                    \
        F3 = feat[(long)p3_ * CHANNELS + lane];                    \
        t += 4;                                                    \
        FLUSH = (t >= cs); SEG = s;                                \
        if (FLUSH) { ++s; t = 0; SKIP_EMPTIES(); } }

    #define CONSUME(F0, F1, F2, F3, FLUSH, SEG) {                  \
        m = fmaxf(m, fmaxf(fmaxf(F0, F1), fmaxf(F2, F3)));         \
        if (FLUSH) {                                               \
            out[(segbase + SEG) * CHANNELS + lane] = m;            \
            m = -INFINITY; } }

    SKIP_EMPTIES();
    float a0, a1, a2, a3, b0, b1, b2, b3;
    float c0, c1, c2, c3, d0, d1, d2, d3;
    bool flA = false, flB = false, flC = false, flD = false;
    int sgA = 0, sgB = 0, sgC = 0, sgD = 0;
    bool hA = false, hB = false, hC = false, hD = false;

    if (s < SPW) { ISSUE(a0, a1, a2, a3, flA, sgA); hA = true; }
    if (s < SPW) { ISSUE(b0, b1, b2, b3, flB, sgB); hB = true; }
    if (s < SPW) { ISSUE(c0, c1, c2, c3, flC, sgC); hC = true; }
    if (s < SPW) { ISSUE(d0, d1, d2, d3, flD, sgD); hD = true; }

    for (;;) {
        if (!hA) break;
        CONSUME(a0, a1, a2, a3, flA, sgA); hA = false;
        if (s < SPW) { ISSUE(a0, a1, a2, a3, flA, sgA); hA = true; }
        if (!hB) break;
        CONSUME(b0, b1, b2, b3, flB, sgB); hB = false;
        if (s < SPW) { ISSUE(b0, b1, b2, b3, flB, sgB); hB = true; }
        if (!hC) break;
        CONSUME(c0, c1, c2, c3, flC, sgC); hC = false;
        if (s < SPW) { ISSUE(c0, c1, c2, c3, flC, sgC); hC = true; }
        if (!hD) break;
        CONSUME(d0, d1, d2, d3, flD, sgD); hD = false;
        if (s < SPW) { ISSUE(d0, d1, d2, d3, flD, sgD); hD = true; }
    }
    // order-preserving drain: exactly one of the four breaks fired
    if (!hA) {
        if (hB) CONSUME(b0, b1, b2, b3, flB, sgB);
        if (hC) CONSUME(c0, c1, c2, c3, flC, sgC);
        if (hD) CONSUME(d0, d1, d2, d3, flD, sgD);
    } else if (!hB) {
        if (hC) CONSUME(c0, c1, c2, c3, flC, sgC);
        if (hD) CONSUME(d0, d1, d2, d3, flD, sgD);
        CONSUME(a0, a1, a2, a3, flA, sgA);
    } else if (!hC) {
        if (hD) CONSUME(d0, d1, d2, d3, flD, sgD);
        CONSUME(a0, a1, a2, a3, flA, sgA);
        CONSUME(b0, b1, b2, b3, flB, sgB);
    } else {
        CONSUME(a0, a1, a2, a3, flA, sgA);
        CONSUME(b0, b1, b2, b3, flB, sgB);
        CONSUME(c0, c1, c2, c3, flC, sgC);
    }
    #undef SKIP_EMPTIES
    #undef EXTRACT
    #undef ISSUE
    #undef CONSUME
}

// Exact cleanup for bucket-overflow points (empty for this input). CAS float max.
__global__ void overflow_kernel(const float* __restrict__ feat,
                                const int* __restrict__ ovf,
                                float* __restrict__ out) {
    int n = min(ovf[0], MAXOVF);
    int total = n * CHANNELS;
    int stride = gridDim.x * blockDim.x;
    for (int k = blockIdx.x * blockDim.x + threadIdx.x; k < total; k += stride) {
        int e = k >> 6;
        int c = k & 63;
        int p = ovf[16 + 2 * e + 0];
        int seg = ovf[16 + 2 * e + 1];
        float v = feat[(long)p * CHANNELS + c];
        int* addr = (int*)&out[(long)seg * CHANNELS + c];
        int old = *addr;
        while (__int_as_float(old) < v) {
            int assumed = old;
            old = atomicCAS(addr, assumed, __float_as_int(v));
            if (old == assumed) break;
        }
    }
}

extern "C" void kernel_launch(void* const* d_in, const int* in_sizes, int n_in,
                              void* d_out, int out_size, void* d_ws, size_t ws_size,
                              hipStream_t stream) {
    const float* feat = (const float*)d_in[0];
    const int* coords = (const int*)d_in[1];
    int npoints = in_sizes[0] / CHANNELS;  // 1,000,000

    // ws layout (ints): cursor[NSEG] | ovf[16 + 2*MAXOVF] | indices[NSEG*CAP]
    int* cursor  = (int*)d_ws;
    int* ovf     = cursor + NSEG;
    int* indices = ovf + 16 + 2 * MAXOVF;

    const int BLOCK = 256;

    zero_kernel<<<512, BLOCK, 0, stream>>>(cursor, NSEG + 16);

    int grid_pts = (npoints + BLOCK - 1) / BLOCK;
    scatter_kernel<<<grid_pts, BLOCK, 0, stream>>>(coords, cursor, ovf, indices, npoints);

    // 8 segs per wave, 4 waves per block -> 32 segs per block
    int grid_gather = NSEG / (SPW * (BLOCK / 64));  // 8192
    gather_strip_kernel<<<grid_gather, BLOCK, 0, stream>>>(feat, indices, cursor, (float*)d_out);

    overflow_kernel<<<16, BLOCK, 0, stream>>>(feat, ovf, (float*)d_out);
}

// Round 8
// 142.028 us; speedup vs baseline: 1.1577x; 1.0249x over previous
//
#include <hip/hip_runtime.h>
#include <math.h>

// Sparse 3D max-pool (kernel=stride=2), gather v7: strip-per-wave,
// 4-rows-per-instruction (dwordx4) + 3-slot software pipeline.
// zero -> bucket scatter -> strip gather -> overflow CAS cleanup (empty).

#define CHANNELS 64
#define COARSE_RES 64
#define NSEG (COARSE_RES * COARSE_RES * COARSE_RES)  // 262144
#define CAP 16
#define MAXOVF 65536
#define SPW 8  // segments per wave

__global__ void zero_kernel(int* __restrict__ buf, int n) {
    int i = blockIdx.x * blockDim.x + threadIdx.x;
    int stride = gridDim.x * blockDim.x;
    for (; i < n; i += stride) buf[i] = 0;
}

__global__ void scatter_kernel(const int* __restrict__ coords,
                               int* __restrict__ cursor,
                               int* __restrict__ ovf,       // [0]=count, data at +16
                               int* __restrict__ indices,
                               int n) {
    int p = blockIdx.x * blockDim.x + threadIdx.x;
    if (p >= n) return;
    int ci = coords[3 * p + 0] >> 1;
    int cj = coords[3 * p + 1] >> 1;
    int ck = coords[3 * p + 2] >> 1;
    int seg = (ci * COARSE_RES + cj) * COARSE_RES + ck;
    int pos = atomicAdd(&cursor[seg], 1);
    if (pos < CAP) {
        indices[seg * CAP + pos] = p;
    } else {
        int o = atomicAdd(&ovf[0], 1);
        if (o < MAXOVF) {
            ovf[16 + 2 * o + 0] = p;
            ovf[16 + 2 * o + 1] = seg;
        }
    }
}

// One wave per 8 consecutive segments. lane=(g,q): g=lane>>4 row-in-chunk,
// q=lane&15 float4-of-channels. One dwordx4 load fetches a 4-row chunk (1KB).
// Per-lane index extraction: 2 shfls per chunk (parallel, not 4 serial).
// 3-slot rotating pipeline keeps 12 rows (3KB) in flight per wave.
__global__ __launch_bounds__(256) void gather_strip_kernel(
        const float* __restrict__ feat,
        const int* __restrict__ indices,
        const int* __restrict__ cursor,
        float* __restrict__ out) {
    int wave = (blockIdx.x * blockDim.x + threadIdx.x) >> 6;
    int lane = threadIdx.x & 63;
    int g = lane >> 4;
    int q = lane & 15;
    long segbase = (long)wave * SPW;
    const float4* feat4 = reinterpret_cast<const float4*>(feat);
    float4* out4 = reinterpret_cast<float4*>(out);

    int cnt_l = 0;
    if (lane < SPW) {
        cnt_l = cursor[segbase + lane];
        if (cnt_l > CAP) cnt_l = CAP;
    }
    // 128 bucket indices of the strip: 2 ints per lane, coalesced 512B
    int2 idx2 = reinterpret_cast<const int2*>(indices + segbase * CAP)[lane];

    int s = 0, t = 0, cs = 0;
    const float4 Z4 = make_float4(0.f, 0.f, 0.f, 0.f);
    const float4 NEG4 = make_float4(-INFINITY, -INFINITY, -INFINITY, -INFINITY);
    float4 m = NEG4;

    #define SKIP_EMPTIES()                                         \
        for (;;) {                                                 \
            if (s >= SPW) break;                                   \
            cs = __shfl(cnt_l, s);                                 \
            if (cs > 0) break;                                     \
            if (lane < 16) out4[(segbase + s) * 16 + q] = Z4;      \
            ++s;                                                   \
        }

    // one chunk: each lane extracts the index of row (t+g) clamped, then one
    // dwordx4 load covers 4 rows x 64 channels. Advances the walk.
    #define ISSUE(F, FLUSH, SEG) {                                 \
        int r_ = t + g;                                            \
        if (r_ > cs - 1) r_ = cs - 1;                              \
        int pos_ = (s << 4) + r_;                                  \
        int lo_ = __shfl(idx2.x, pos_ >> 1);                       \
        int hi_ = __shfl(idx2.y, pos_ >> 1);                       \
        int p_ = (pos_ & 1) ? hi_ : lo_;                           \
        F = feat4[(long)p_ * 16 + q];                              \
        t += 4;                                                    \
        FLUSH = (t >= cs); SEG = s;                                \
        if (FLUSH) { ++s; t = 0; SKIP_EMPTIES(); } }

    #define CONSUME(F, FLUSH, SEG) {                               \
        m.x = fmaxf(m.x, F.x); m.y = fmaxf(m.y, F.y);              \
        m.z = fmaxf(m.z, F.z); m.w = fmaxf(m.w, F.w);              \
        if (FLUSH) {                                               \
            m.x = fmaxf(m.x, __shfl_xor(m.x, 16));                 \
            m.y = fmaxf(m.y, __shfl_xor(m.y, 16));                 \
            m.z = fmaxf(m.z, __shfl_xor(m.z, 16));                 \
            m.w = fmaxf(m.w, __shfl_xor(m.w, 16));                 \
            m.x = fmaxf(m.x, __shfl_xor(m.x, 32));                 \
            m.y = fmaxf(m.y, __shfl_xor(m.y, 32));                 \
            m.z = fmaxf(m.z, __shfl_xor(m.z, 32));                 \
            m.w = fmaxf(m.w, __shfl_xor(m.w, 32));                 \
            if (lane < 16) out4[(segbase + SEG) * 16 + q] = m;     \
            m = NEG4; } }

    SKIP_EMPTIES();
    float4 A, B, C;
    bool flA = false, flB = false, flC = false;
    int sgA = 0, sgB = 0, sgC = 0;
    bool hA = false, hB = false, hC = false;

    if (s < SPW) { ISSUE(A, flA, sgA); hA = true; }
    if (s < SPW) { ISSUE(B, flB, sgB); hB = true; }
    if (s < SPW) { ISSUE(C, flC, sgC); hC = true; }

    for (;;) {
        if (!hA) break;
        CONSUME(A, flA, sgA); hA = false;
        if (s < SPW) { ISSUE(A, flA, sgA); hA = true; }
        if (!hB) break;
        CONSUME(B, flB, sgB); hB = false;
        if (s < SPW) { ISSUE(B, flB, sgB); hB = true; }
        if (!hC) break;
        CONSUME(C, flC, sgC); hC = false;
        if (s < SPW) { ISSUE(C, flC, sgC); hC = true; }
    }
    // order-preserving drain (issue order among live slots)
    if (!hA) {
        if (hB) CONSUME(B, flB, sgB);
        if (hC) CONSUME(C, flC, sgC);
    } else if (!hB) {
        if (hC) CONSUME(C, flC, sgC);
        CONSUME(A, flA, sgA);
    } else {
        CONSUME(A, flA, sgA);
        CONSUME(B, flB, sgB);
    }
    #undef SKIP_EMPTIES
    #undef ISSUE
    #undef CONSUME
}

// Exact cleanup for bucket-overflow points (empty for this input). CAS float max.
__global__ void overflow_kernel(const float* __restrict__ feat,
                                const int* __restrict__ ovf,
                                float* __restrict__ out) {
    int n = min(ovf[0], MAXOVF);
    int total = n * CHANNELS;
    int stride = gridDim.x * blockDim.x;
    for (int k = blockIdx.x * blockDim.x + threadIdx.x; k < total; k += stride) {
        int e = k >> 6;
        int c = k & 63;
        int p = ovf[16 + 2 * e + 0];
        int seg = ovf[16 + 2 * e + 1];
        float v = feat[(long)p * CHANNELS + c];
        int* addr = (int*)&out[(long)seg * CHANNELS + c];
        int old = *addr;
        while (__int_as_float(old) < v) {
            int assumed = old;
            old = atomicCAS(addr, assumed, __float_as_int(v));
            if (old == assumed) break;
        }
    }
}

extern "C" void kernel_launch(void* const* d_in, const int* in_sizes, int n_in,
                              void* d_out, int out_size, void* d_ws, size_t ws_size,
                              hipStream_t stream) {
    const float* feat = (const float*)d_in[0];
    const int* coords = (const int*)d_in[1];
    int npoints = in_sizes[0] / CHANNELS;  // 1,000,000

    // ws layout (ints): cursor[NSEG] | ovf[16 + 2*MAXOVF] | indices[NSEG*CAP]
    int* cursor  = (int*)d_ws;
    int* ovf     = cursor + NSEG;
    int* indices = ovf + 16 + 2 * MAXOVF;

    const int BLOCK = 256;

    zero_kernel<<<512, BLOCK, 0, stream>>>(cursor, NSEG + 16);

    int grid_pts = (npoints + BLOCK - 1) / BLOCK;
    scatter_kernel<<<grid_pts, BLOCK, 0, stream>>>(coords, cursor, ovf, indices, npoints);

    // 8 segs per wave, 4 waves per block -> 32 segs per block
    int grid_gather = NSEG / (SPW * (BLOCK / 64));  // 8192
    gather_strip_kernel<<<grid_gather, BLOCK, 0, stream>>>(feat, indices, cursor, (float*)d_out);

    overflow_kernel<<<16, BLOCK, 0, stream>>>(feat, ovf, (float*)d_out);
}

// Round 9
// 141.115 us; speedup vs baseline: 1.1652x; 1.0065x over previous
//
#include <hip/hip_runtime.h>
#include <math.h>

// Sparse 3D max-pool (kernel=stride=2), gather v8: R5 champion structure
// (strip-per-wave, 2-slot pipeline) + non-temporal hints on the zero-reuse
// feature loads and output stores.
// zero -> bucket scatter -> strip gather -> overflow CAS cleanup (empty).

#define CHANNELS 64
#define COARSE_RES 64
#define NSEG (COARSE_RES * COARSE_RES * COARSE_RES)  // 262144
#define CAP 16
#define MAXOVF 65536
#define SPW 8  // segments per wave

__global__ void zero_kernel(int* __restrict__ buf, int n) {
    int i = blockIdx.x * blockDim.x + threadIdx.x;
    int stride = gridDim.x * blockDim.x;
    for (; i < n; i += stride) buf[i] = 0;
}

__global__ void scatter_kernel(const int* __restrict__ coords,
                               int* __restrict__ cursor,
                               int* __restrict__ ovf,       // [0]=count, data at +16
                               int* __restrict__ indices,
                               int n) {
    int p = blockIdx.x * blockDim.x + threadIdx.x;
    if (p >= n) return;
    int ci = coords[3 * p + 0] >> 1;
    int cj = coords[3 * p + 1] >> 1;
    int ck = coords[3 * p + 2] >> 1;
    int seg = (ci * COARSE_RES + cj) * COARSE_RES + ck;
    int pos = atomicAdd(&cursor[seg], 1);
    if (pos < CAP) {
        indices[seg * CAP + pos] = p;
    } else {
        int o = atomicAdd(&ovf[0], 1);
        if (o < MAXOVF) {
            ovf[16 + 2 * o + 0] = p;
            ovf[16 + 2 * o + 1] = seg;
        }
    }
}

// One wave per 8 consecutive segments; counts + 128 bucket indices preloaded
// into registers; 2-slot ping-pong pipeline of 4-row chunks. Feature loads and
// output stores are non-temporal (zero reuse within the dispatch).
__global__ __launch_bounds__(256) void gather_strip_kernel(
        const float* __restrict__ feat,
        const int* __restrict__ indices,
        const int* __restrict__ cursor,
        float* __restrict__ out) {
    int wave = (blockIdx.x * blockDim.x + threadIdx.x) >> 6;
    int lane = threadIdx.x & 63;
    long segbase = (long)wave * SPW;

    int cnt_l = 0;
    if (lane < SPW) {
        cnt_l = cursor[segbase + lane];
        if (cnt_l > CAP) cnt_l = CAP;
    }
    // 128 indices of the strip: 2 ints per lane, fully coalesced 512B
    int2 idx2 = reinterpret_cast<const int2*>(indices + segbase * CAP)[lane];

    int s = 0, t = 0, cs = 0;
    float m = -INFINITY;

    #define SKIP_EMPTIES()                                         \
        for (;;) {                                                 \
            if (s >= SPW) break;                                   \
            cs = __shfl(cnt_l, s);                                 \
            if (cs > 0) break;                                     \
            __builtin_nontemporal_store(0.0f,                      \
                &out[(segbase + s) * CHANNELS + lane]);            \
            ++s;                                                   \
        }

    #define EXTRACT(r, dst) {                                      \
        int lsrc = (s << 3) + ((r) >> 1);                          \
        int lo_ = __shfl(idx2.x, lsrc);                            \
        int hi_ = __shfl(idx2.y, lsrc);                            \
        dst = ((r) & 1) ? hi_ : lo_; }

    #define ISSUE(F0, F1, F2, F3, FLUSH, SEG) {                    \
        int r1_ = min(t + 1, cs - 1);                              \
        int r2_ = min(t + 2, cs - 1);                              \
        int r3_ = min(t + 3, cs - 1);                              \
        int p0_, p1_, p2_, p3_;                                    \
        EXTRACT(t,   p0_); EXTRACT(r1_, p1_);                      \
        EXTRACT(r2_, p2_); EXTRACT(r3_, p3_);                      \
        F0 = __builtin_nontemporal_load(&feat[(long)p0_ * CHANNELS + lane]); \
        F1 = __builtin_nontemporal_load(&feat[(long)p1_ * CHANNELS + lane]); \
        F2 = __builtin_nontemporal_load(&feat[(long)p2_ * CHANNELS + lane]); \
        F3 = __builtin_nontemporal_load(&feat[(long)p3_ * CHANNELS + lane]); \
        t += 4;                                                    \
        FLUSH = (t >= cs); SEG = s;                                \
        if (FLUSH) { ++s; t = 0; SKIP_EMPTIES(); } }

    #define CONSUME(F0, F1, F2, F3, FLUSH, SEG) {                  \
        m = fmaxf(m, fmaxf(fmaxf(F0, F1), fmaxf(F2, F3)));         \
        if (FLUSH) {                                               \
            __builtin_nontemporal_store(m,                         \
                &out[(segbase + SEG) * CHANNELS + lane]);          \
            m = -INFINITY; } }

    SKIP_EMPTIES();
    float fA0, fA1, fA2, fA3, fB0, fB1, fB2, fB3;
    bool flA = false, flB = false;
    int sgA = 0, sgB = 0;
    bool haveA = false, haveB = false;
    if (s < SPW) { ISSUE(fA0, fA1, fA2, fA3, flA, sgA); haveA = true; }
    if (s < SPW) { ISSUE(fB0, fB1, fB2, fB3, flB, sgB); haveB = true; }
    while (haveA) {
        CONSUME(fA0, fA1, fA2, fA3, flA, sgA); haveA = false;
        if (s < SPW) { ISSUE(fA0, fA1, fA2, fA3, flA, sgA); haveA = true; }
        if (!haveB) { if (!haveA) break; else continue; }
        CONSUME(fB0, fB1, fB2, fB3, flB, sgB); haveB = false;
        if (s < SPW) { ISSUE(fB0, fB1, fB2, fB3, flB, sgB); haveB = true; }
    }
    #undef SKIP_EMPTIES
    #undef EXTRACT
    #undef ISSUE
    #undef CONSUME
}

// Exact cleanup for bucket-overflow points (empty for this input). CAS float max.
__global__ void overflow_kernel(const float* __restrict__ feat,
                                const int* __restrict__ ovf,
                                float* __restrict__ out) {
    int n = min(ovf[0], MAXOVF);
    int total = n * CHANNELS;
    int stride = gridDim.x * blockDim.x;
    for (int k = blockIdx.x * blockDim.x + threadIdx.x; k < total; k += stride) {
        int e = k >> 6;
        int c = k & 63;
        int p = ovf[16 + 2 * e + 0];
        int seg = ovf[16 + 2 * e + 1];
        float v = feat[(long)p * CHANNELS + c];
        int* addr = (int*)&out[(long)seg * CHANNELS + c];
        int old = *addr;
        while (__int_as_float(old) < v) {
            int assumed = old;
            old = atomicCAS(addr, assumed, __float_as_int(v));
            if (old == assumed) break;
        }
    }
}

extern "C" void kernel_launch(void* const* d_in, const int* in_sizes, int n_in,
                              void* d_out, int out_size, void* d_ws, size_t ws_size,
                              hipStream_t stream) {
    const float* feat = (const float*)d_in[0];
    const int* coords = (const int*)d_in[1];
    int npoints = in_sizes[0] / CHANNELS;  // 1,000,000

    // ws layout (ints): cursor[NSEG] | ovf[16 + 2*MAXOVF] | indices[NSEG*CAP]
    int* cursor  = (int*)d_ws;
    int* ovf     = cursor + NSEG;
    int* indices = ovf + 16 + 2 * MAXOVF;

    const int BLOCK = 256;

    zero_kernel<<<512, BLOCK, 0, stream>>>(cursor, NSEG + 16);

    int grid_pts = (npoints + BLOCK - 1) / BLOCK;
    scatter_kernel<<<grid_pts, BLOCK, 0, stream>>>(coords, cursor, ovf, indices, npoints);

    // 8 segs per wave, 4 waves per block -> 32 segs per block
    int grid_gather = NSEG / (SPW * (BLOCK / 64));  // 8192
    gather_strip_kernel<<<grid_gather, BLOCK, 0, stream>>>(feat, indices, cursor, (float*)d_out);

    overflow_kernel<<<16, BLOCK, 0, stream>>>(feat, ovf, (float*)d_out);
}